// Round 21
// baseline (155.909 us; speedup 1.0000x reference)
//
#include <hip/hip_runtime.h>
#include <math.h>

#define NB 4
#define SEQ 1024
#define DMODEL 1024
#define NHEAD 16
#define DHEAD 64

typedef __attribute__((ext_vector_type(8))) short s16x8;
typedef __attribute__((ext_vector_type(4))) short s16x4;
typedef __attribute__((ext_vector_type(4))) float f32x4;

__device__ __forceinline__ short f2bf(float f) {
    union { float f; unsigned u; } x; x.f = f;
    unsigned r = x.u + 0x7fffu + ((x.u >> 16) & 1u);   // RNE
    return (short)(r >> 16);
}

__device__ __forceinline__ unsigned cvtpk(float lo, float hi) {
    unsigned r;
    asm("v_cvt_pk_bf16_f32 %0, %1, %2" : "=v"(r) : "v"(lo), "v"(hi));
    return r;   // lo -> [15:0], hi -> [31:16], RNE
}

__device__ __forceinline__ f32x4 mfma16(s16x8 a, s16x8 b, f32x4 c) {
    return __builtin_amdgcn_mfma_f32_16x16x32_bf16(a, b, c, 0, 0, 0);
}

__device__ __forceinline__ s16x8 cvt8(float4 a, float4 b) {
    s16x8 v;
    v[0] = f2bf(a.x); v[1] = f2bf(a.y); v[2] = f2bf(a.z); v[3] = f2bf(a.w);
    v[4] = f2bf(b.x); v[5] = f2bf(b.y); v[6] = f2bf(b.z); v[7] = f2bf(b.w);
    return v;
}

__device__ __forceinline__ s16x8 ldlds(const short* base, int byteoff) {
    return *(const s16x8*)((const char*)base + byteoff);
}

#define GLDS16(g, l) __builtin_amdgcn_global_load_lds( \
    (const __attribute__((address_space(1))) unsigned int*)(g), \
    (__attribute__((address_space(3))) unsigned int*)(l), 16, 0, 0)
#define GLDS4(g, l) __builtin_amdgcn_global_load_lds( \
    (const __attribute__((address_space(1))) unsigned int*)(g), \
    (__attribute__((address_space(3))) unsigned int*)(l), 4, 0, 0)

// ---------------------------------------------------------------------------
// prep_a: pre-passes gemm1 DEPENDS on.
//   [0,2048)      convert embed fp32 -> bf16 (ebf)
//   [2048,3072)   transpose Wqkv -> WqkvT bf16
// ---------------------------------------------------------------------------
__global__ __launch_bounds__(256) void prep_a_kernel(
    const float* __restrict__ embed, const float* __restrict__ Wqkv,
    short* __restrict__ ebf, short* __restrict__ WqkvT)
{
    __shared__ __align__(16) char smem[9216];
    int gb = blockIdx.x;
    int tid = threadIdx.x;

    if (gb < 2048) {
        int i = (gb * 256 + tid) * 8;
        float4 a = *(const float4*)(embed + i);
        float4 b = *(const float4*)(embed + i + 4);
        *(s16x8*)(ebf + i) = cvt8(a, b);
    } else {
        int t = gb - 2048;                 // 64 x 16 tiles
        int bx = t & 63, by = t >> 6;
        const int N = 4096;
        short (*T)[72] = (short(*)[72])smem;
        int nt = bx * 64, kt = by * 64;
        int kl = tid >> 4;
        int nl = (tid & 15) * 4;
        #pragma unroll
        for (int rr = 0; rr < 4; ++rr) {
            int k = kl + rr * 16;
            float4 v = *(const float4*)(Wqkv + (size_t)(kt + k) * N + nt + nl);
            T[nl + 0][k] = f2bf(v.x);
            T[nl + 1][k] = f2bf(v.y);
            T[nl + 2][k] = f2bf(v.z);
            T[nl + 3][k] = f2bf(v.w);
        }
        __syncthreads();
        int nr = tid >> 2;
        int kc = (tid & 3) * 16;
        uint4 a = *(const uint4*)&T[nr][kc];
        uint4 b = *(const uint4*)&T[nr][kc + 8];
        short* dst = WqkvT + (size_t)(nt + nr) * 1024 + kt + kc;
        *(uint4*)(dst) = a;
        *(uint4*)(dst + 8) = b;
    }
}

// ---------------------------------------------------------------------------
// gemm_qkv_fused (best measured config): 512-thread blocks, 64KB LDS.
// Blocks [0,256): QKV GEMM 256x256 tile, 8 waves, BK=32, depth-1
//   counted-vmcnt dbuf, 1-D XCD swizzle, scatter epilogue.
// Blocks [256,900): prep_b — tail-fill CUs as gemm blocks retire.
//   [0,4) mask_pack; [4,388) pos_proj; [388,644) WfcT transpose
// ---------------------------------------------------------------------------
__global__ __launch_bounds__(512, 2) void gemm_qkv_fused(
    const short* __restrict__ A, const short* __restrict__ BT,
    short* __restrict__ o0, short* __restrict__ o1, short* __restrict__ o2,
    short* __restrict__ o3,
    const int* __restrict__ qmask, const int* __restrict__ umask,
    const float* __restrict__ Wpos, const float* __restrict__ Wfc,
    int* __restrict__ PM, short* __restrict__ qpb, short* __restrict__ WfcT)
{
    __shared__ short As[2][256 * 32];      // 16KB per buffer
    __shared__ short Bs[2][256 * 32];

    int gb = blockIdx.x;
    int tid = threadIdx.x;

    if (gb >= 256) {
        int pb = gb - 256;
        char* smem = (char*)&As[0][0];
        if (pb < 4) {
            // ------- mask_pack -------
            if (tid < 256) {
                int b = pb;
                for (int k = tid; k < 1088; k += 256) {
                    int v = 2;
                    if (k < 1024)
                        v = (qmask[b * 1024 + k] & 1) | ((umask[b * 1024 + k] == 0) ? 2 : 0);
                    PM[b * 1088 + k] = v;
                }
            }
        } else if (pb < 388) {
            // ------- pos_proj -------
            int bid = pb - 4;
            int s = bid >> 7;
            int l0 = (bid & 127) * 8;
            float (*pe)[64] = (float(*)[64])smem;

            if (tid < 256) {
                for (int idx = tid; idx < 512; idx += 256) {
                    int li = idx >> 6, t = idx & 63;
                    float p = (float)(l0 + li - 512);
                    int j = (t < 32) ? t : (t - 32);
                    float f = expf(-0.2971077539f * (float)j);   // ln(10000)/31
                    float a = p * f;
                    pe[li][t] = (t < 32) ? sinf(a) : cosf(a);
                }
            }
            __syncthreads();

            if (tid < 256) {
                float acc[4][8] = {};
                const float* wp = Wpos + s * 1024 + tid;
                for (int t = 0; t < 64; ++t) {
                    float w0 = wp[t * 3072];
                    float w1 = wp[t * 3072 + 256];
                    float w2 = wp[t * 3072 + 512];
                    float w3 = wp[t * 3072 + 768];
                    #pragma unroll
                    for (int li = 0; li < 8; ++li) {
                        float pv = pe[li][t];
                        acc[0][li] += pv * w0; acc[1][li] += pv * w1;
                        acc[2][li] += pv * w2; acc[3][li] += pv * w3;
                    }
                }
                #pragma unroll
                for (int cc = 0; cc < 4; ++cc) {
                    int c = tid + cc * 256;
                    int h = c >> 6, d = c & 63;
                    #pragma unroll
                    for (int li = 0; li < 8; ++li) {
                        short bv = f2bf(acc[cc][li]);
                        if (s == 0) {
                            qpb[((size_t)(h << 10) + l0 + li) * 64 + d] = bv;
                        } else {
                            short* dst = (s == 1) ? o1 : o2;   // k1cat / k2cat
                            #pragma unroll
                            for (int bb = 0; bb < 4; ++bb)
                                dst[((size_t)((bb * 16 + h) * 1024) + l0 + li) * 128 + 64 + d] = bv;
                        }
                    }
                }
            }
        } else {
            // ------- WfcT transpose -------
            int t = pb - 388;              // 16 x 16 tiles
            int bx = t & 15, by = t >> 4;
            const int N = 1024;
            short (*T)[72] = (short(*)[72])smem;
            int nt = bx * 64, kt = by * 64;
            if (tid < 256) {
                int kl = tid >> 4;
                int nl = (tid & 15) * 4;
                #pragma unroll
                for (int rr = 0; rr < 4; ++rr) {
                    int k = kl + rr * 16;
                    float4 v = *(const float4*)(Wfc + (size_t)(kt + k) * N + nt + nl);
                    T[nl + 0][k] = f2bf(v.x);
                    T[nl + 1][k] = f2bf(v.y);
                    T[nl + 2][k] = f2bf(v.z);
                    T[nl + 3][k] = f2bf(v.w);
                }
            }
            __syncthreads();
            if (tid < 256) {
                int nr = tid >> 2;
                int kc = (tid & 3) * 16;
                uint4 a = *(const uint4*)&T[nr][kc];
                uint4 b = *(const uint4*)&T[nr][kc + 8];
                short* dst = WfcT + (size_t)(nt + nr) * 1024 + kt + kc;
                *(uint4*)(dst) = a;
                *(uint4*)(dst + 8) = b;
            }
        }
        return;
    }

    // ------------------- QKV GEMM: 256^2 tile, 8 waves, depth-1 -----------
    int lin = gb;                          // 0..255
    int swb = (lin & 7) * 32 + (lin >> 3); // 1-D XCD swizzle (bijective)
    int bx = swb & 15, by = swb >> 4;      // grid 16 x 16
    int m0 = by * 256, n0 = bx * 256;

    int w = tid >> 6, lane = tid & 63;     // w in [0,8)
    int wm = w >> 2, wn = w & 3;           // 2 x 4 wave grid
    int lq = lane & 15, lg = lane >> 4;

    f32x4 zero = {0.f, 0.f, 0.f, 0.f};
    f32x4 acc[8][4];
    #pragma unroll
    for (int i = 0; i < 8; ++i)
        #pragma unroll
        for (int jj = 0; jj < 4; ++jj) acc[i][jj] = zero;

    int swz = (((lane & 3) ^ ((lane >> 2) & 3)) << 3);
    int srow = lane >> 2;
    const short* aBase = A  + (size_t)(m0 + (w << 5) + srow) * 1024 + swz;
    const short* bBase = BT + (size_t)(n0 + (w << 5) + srow) * 1024 + swz;
    int dOff = w * 1024;                   // wave region: 32 rows x 32 shorts

    GLDS16(aBase, &As[0][dOff]);
    GLDS16(aBase + 16 * 1024, &As[0][dOff + 512]);
    GLDS16(bBase, &Bs[0][dOff]);
    GLDS16(bBase + 16 * 1024, &Bs[0][dOff + 512]);

    int cur = 0;
    for (int kt = 0; kt < 1024; kt += 32) {
        if (kt + 32 < 1024) {
            int nxt = cur ^ 1;
            GLDS16(aBase + kt + 32, &As[nxt][dOff]);
            GLDS16(aBase + kt + 32 + 16 * 1024, &As[nxt][dOff + 512]);
            GLDS16(bBase + kt + 32, &Bs[nxt][dOff]);
            GLDS16(bBase + kt + 32 + 16 * 1024, &Bs[nxt][dOff + 512]);
            asm volatile("s_waitcnt vmcnt(4)" ::: "memory");
        } else {
            asm volatile("s_waitcnt vmcnt(0)" ::: "memory");
        }
        __builtin_amdgcn_s_barrier();      // all waves: tile kt resident
        asm volatile("" ::: "memory");

        s16x8 bfr[4];
        #pragma unroll
        for (int nt = 0; nt < 4; ++nt) {
            int row = wn * 64 + nt * 16 + lq;
            bfr[nt] = ldlds(Bs[cur], (row * 64 + lg * 16) ^ ((row & 3) << 4));
        }
        #pragma unroll
        for (int mt = 0; mt < 8; ++mt) {
            int row = wm * 128 + mt * 16 + lq;
            s16x8 af = ldlds(As[cur], (row * 64 + lg * 16) ^ ((row & 3) << 4));
            #pragma unroll
            for (int nt = 0; nt < 4; ++nt)
                acc[mt][nt] = mfma16(af, bfr[nt], acc[mt][nt]);
        }

        asm volatile("" ::: "memory");
        __builtin_amdgcn_s_barrier();      // buf[cur] free for overwrite
        cur ^= 1;
    }

    // scatter epilogue (128x64 per wave)
    #pragma unroll
    for (int nt = 0; nt < 4; ++nt) {
        int n = n0 + wn * 64 + nt * 16 + lq;
        int sec = n >> 10, hd = n & 1023;
        int hh = hd >> 6, d = hd & 63;
        #pragma unroll
        for (int mt = 0; mt < 8; ++mt) {
            int mb = m0 + wm * 128 + mt * 16 + lg * 4;
            int b = mb >> 10, li0 = mb & 1023;
            int bh = b * 16 + hh;
            if (sec == 3) {
                s16x4 pv;
                #pragma unroll
                for (int r = 0; r < 4; ++r) pv[r] = f2bf(acc[mt][nt][r]);
                *(s16x4*)(o3 + (((size_t)(bh * 64 + d)) << 10) + li0) = pv;
            } else {
                #pragma unroll
                for (int r = 0; r < 4; ++r) {
                    short bv = f2bf(acc[mt][nt][r]);
                    if (sec == 0)
                        o0[((size_t)(bh << 10) + li0 + r) * 64 + d] = bv;
                    else if (sec == 1)
                        o1[((size_t)bh * 1024 + li0 + r) * 128 + d] = bv;
                    else
                        o2[((size_t)bh * 1024 + li0 + r) * 128 + d] = bv;
                }
            }
        }
    }
}

// ---------------------------------------------------------------------------
// gemm_nt (EPI==1 only): final projection ctx @ WfcT -> out fp32.
// R8 structure: depth-1 counted-vmcnt dbuf, 1-D XCD swizzle.
// ---------------------------------------------------------------------------
template<int EPI, int NCOLS>
__global__ __launch_bounds__(256) void gemm_nt(
    const short* __restrict__ A, const short* __restrict__ BT,
    float* __restrict__ of)
{
    __shared__ short As[2][128 * 32];
    __shared__ short Bs[2][128 * 32];

    int nwg = gridDim.x * gridDim.y;
    int lin = blockIdx.y * gridDim.x + blockIdx.x;
    int cpx = nwg >> 3;
    int swb = (lin & 7) * cpx + (lin >> 3);
    int bx = swb % gridDim.x, by = swb / gridDim.x;
    int m0 = by * 128, n0 = bx * 128;

    int tid = threadIdx.x;
    int w = tid >> 6, lane = tid & 63;
    int wm = w >> 1, wn = w & 1;
    int lq = lane & 15, lg = lane >> 4;

    f32x4 zero = {0.f, 0.f, 0.f, 0.f};
    f32x4 acc[4][4];
    #pragma unroll
    for (int i = 0; i < 4; ++i)
        #pragma unroll
        for (int j = 0; j < 4; ++j) acc[i][j] = zero;

    int swz = (((lane & 3) ^ ((lane >> 2) & 3)) << 3);
    int srow = lane >> 2;
    const short* aBase = A  + (size_t)(m0 + (w << 5) + srow) * 1024 + swz;
    const short* bBase = BT + (size_t)(n0 + (w << 5) + srow) * 1024 + swz;
    int dOff = w * 1024;

    GLDS16(aBase, &As[0][dOff]);
    GLDS16(aBase + 16 * 1024, &As[0][dOff + 512]);
    GLDS16(bBase, &Bs[0][dOff]);
    GLDS16(bBase + 16 * 1024, &Bs[0][dOff + 512]);

    int cur = 0;
    for (int kt = 0; kt < 1024; kt += 32) {
        if (kt + 32 < 1024) {
            int nxt = cur ^ 1;
            GLDS16(aBase + kt + 32, &As[nxt][dOff]);
            GLDS16(aBase + kt + 32 + 16 * 1024, &As[nxt][dOff + 512]);
            GLDS16(bBase + kt + 32, &Bs[nxt][dOff]);
            GLDS16(bBase + kt + 32 + 16 * 1024, &Bs[nxt][dOff + 512]);
            asm volatile("s_waitcnt vmcnt(4)" ::: "memory");
        } else {
            asm volatile("s_waitcnt vmcnt(0)" ::: "memory");
        }
        __builtin_amdgcn_s_barrier();
        asm volatile("" ::: "memory");

        s16x8 af[4], bfr[4];
        #pragma unroll
        for (int mt = 0; mt < 4; ++mt) {
            int row = wm * 64 + mt * 16 + lq;
            af[mt] = ldlds(As[cur], (row * 64 + lg * 16) ^ ((row & 3) << 4));
        }
        #pragma unroll
        for (int nt = 0; nt < 4; ++nt) {
            int row = wn * 64 + nt * 16 + lq;
            bfr[nt] = ldlds(Bs[cur], (row * 64 + lg * 16) ^ ((row & 3) << 4));
        }
        #pragma unroll
        for (int mt = 0; mt < 4; ++mt)
            #pragma unroll
            for (int nt = 0; nt < 4; ++nt)
                acc[mt][nt] = mfma16(af[mt], bfr[nt], acc[mt][nt]);

        asm volatile("" ::: "memory");
        __builtin_amdgcn_s_barrier();
        cur ^= 1;
    }

    #pragma unroll
    for (int nt = 0; nt < 4; ++nt) {
        int n = n0 + wn * 64 + nt * 16 + lq;
        #pragma unroll
        for (int mt = 0; mt < 4; ++mt) {
            int mb = m0 + wm * 64 + mt * 16 + lg * 4;
            #pragma unroll
            for (int r = 0; r < 4; ++r)
                of[(size_t)(mb + r) * NCOLS + n] = acc[mt][nt][r];
        }
    }
}

// ---------------------------------------------------------------------------
// attn: flash attention (best measured, 64.9 us): grid 1024 = 64 bh x
// 16 q-tiles, bh = xg*8+(j&7) / qt = 15-(j>>3) (load-balance-optimal map);
// K double-buffered via counted vmcnt; V single-buffered staged at loop
// bottom; defer-max, cvt_pk, setprio, b128 mask reads.
// ---------------------------------------------------------------------------
__global__ __launch_bounds__(256) void attn_kernel(
    const short* __restrict__ qb, const short* __restrict__ k1cat,
    const short* __restrict__ k2cat, const short* __restrict__ vtb,
    const short* __restrict__ qpb, const int* __restrict__ PM,
    const int* __restrict__ qmask, short* __restrict__ ctx)
{
    __shared__ short K1s[2][32 * 128];
    __shared__ short K2s[2][32 * 128];
    __shared__ short Vs[64 * 32];         // single buffer (staged post-barrier)
    __shared__ int   PMs[2][64];

    int bid = blockIdx.x;                 // 1024 blocks
    int xg = bid & 7, j = bid >> 3;       // xg = XCD, j in [0,128)
    int bh = xg * 8 + (j & 7);            // 8 bh panels per XCD (L2 reuse)
    int qt = 15 - (j >> 3);               // descending qt: big blocks first
    int b = bh >> 4, h = bh & 15;

    int w = threadIdx.x >> 6, lane = threadIdx.x & 63;
    int lq = lane & 15, lg = lane >> 4;

    auto STAGE_K = [&](int d, int K0) {
        #pragma unroll
        for (int i = 0; i < 4; ++i) {
            int g = w * 4 + i;
            if (g < 8) {
                int row = g * 4 + (lane >> 4);
                int colb = ((lane & 15) << 4) ^ ((row & 7) << 4);
                const short* src = k1cat + ((size_t)bh * 1024 + K0 + row) * 128 + (colb >> 1);
                GLDS16(src, &K1s[d][g * 512]);
            } else {
                int gg = g - 8;
                int row = gg * 4 + (lane >> 4);
                int colb = ((lane & 15) << 4) ^ ((row & 7) << 4);
                const short* src = k2cat + ((size_t)bh * 1024 + K0 + row) * 128 + (colb >> 1);
                GLDS16(src, &K2s[d][gg * 512]);
            }
        }
        if (w == 0) {
            GLDS4(PM + b * 1088 + K0 + lane, &PMs[d][0]);
        }
    };
    auto STAGE_V = [&](int K0) {
        int row = w * 16 + (lane >> 2);
        int colb = ((lane & 3) << 4) ^ ((row & 3) << 4);
        const short* src = vtb + ((size_t)bh * 64 + row) * 1024 + K0 + (colb >> 1);
        GLDS16(src, &Vs[w * 512]);
    };

    f32x4 zero = {0.f, 0.f, 0.f, 0.f};

    int q0 = qt * 64 + w * 16;
    int q_glob = q0 + lq;

    const short* qrow  = qb  + ((size_t)bh * SEQ + q_glob) * DHEAD;
    const short* qprow = qpb + ((size_t)h  * SEQ + q_glob) * DHEAD;
    s16x8 qf0  = *(const s16x8*)(qrow + lg * 8);
    s16x8 qf1  = *(const s16x8*)(qrow + 32 + lg * 8);
    s16x8 qpf0 = *(const s16x8*)(qprow + lg * 8);
    s16x8 qpf1 = *(const s16x8*)(qprow + 32 + lg * 8);
    int qm_q = qmask[b * SEQ + q_glob] & 1;
    asm volatile("s_waitcnt vmcnt(0)" ::: "memory");

    f32x4 accO[4];
    #pragma unroll
    for (int i = 0; i < 4; ++i) accO[i] = zero;
    float m_run = -1e30f, l_run = 0.f;

    int nslab = 2 * qt + 2;
    STAGE_K(0, 0);
    STAGE_V(0);

    #pragma unroll 1
    for (int t = 0; t < nslab; ++t) {
        int cur = t & 1;
        if (t + 1 < nslab) {
            STAGE_K(cur ^ 1, (t + 1) * 32);
            if (w == 0) asm volatile("s_waitcnt vmcnt(5)" ::: "memory");
            else        asm volatile("s_waitcnt vmcnt(4)" ::: "memory");
        } else {
            asm volatile("s_waitcnt vmcnt(0)" ::: "memory");
        }
        __builtin_amdgcn_s_barrier();
        asm volatile("" ::: "memory");

        int K0 = t * 32;
        if (K0 <= q0 + 15) {
            const short* b1 = K1s[cur];
            const short* b2 = K2s[cur];

            f32x4 s1v[2], s2v[2];
            __builtin_amdgcn_s_setprio(1);
            #pragma unroll
            for (int hh = 0; hh < 2; ++hh) {
                int row = hh * 16 + lq;
                int ro = row * 256 + (lg << 4);
                int sw = (row & 7) << 4;
                f32x4 tv = zero, uv = zero;
                tv = mfma16(ldlds(b1, (ro      ) ^ sw), qf0,  tv);
                tv = mfma16(ldlds(b1, (ro +  64) ^ sw), qf1,  tv);
                tv = mfma16(ldlds(b1, (ro + 128) ^ sw), qpf0, tv);
                tv = mfma16(ldlds(b1, (ro + 192) ^ sw), qpf1, tv);
                s1v[hh] = tv;
                uv = mfma16(ldlds(b2, (ro      ) ^ sw), qf0,  uv);
                uv = mfma16(ldlds(b2, (ro +  64) ^ sw), qf1,  uv);
                uv = mfma16(ldlds(b2, (ro + 128) ^ sw), qpf0, uv);
                uv = mfma16(ldlds(b2, (ro + 192) ^ sw), qpf1, uv);
                s2v[hh] = uv;
            }
            __builtin_amdgcn_s_setprio(0);

            int4 pmv0 = *(const int4*)&PMs[cur][lg * 4];
            int4 pmv1 = *(const int4*)&PMs[cur][16 + lg * 4];
            int pme[8] = {pmv0.x, pmv0.y, pmv0.z, pmv0.w,
                          pmv1.x, pmv1.y, pmv1.z, pmv1.w};

            float sv[8];
            #pragma unroll
            for (int i = 0; i < 8; ++i) {
                int hh = i >> 2, r = i & 3;
                int k_idx = K0 + hh * 16 + lg * 4 + r;
                int pm = pme[i];
                float s = ((pm & 1) == qm_q) ? s1v[hh][r] : s2v[hh][r];
                if (k_idx > q_glob || (pm & 2)) s = -INFINITY;
                sv[i] = s;
            }
            float tm = sv[0];
            #pragma unroll
            for (int i = 1; i < 8; ++i) tm = fmaxf(tm, sv[i]);
            tm = fmaxf(tm, __shfl_xor(tm, 16));
            tm = fmaxf(tm, __shfl_xor(tm, 32));

            if (!__all(tm <= m_run + 8.0f)) {
                float m_new = fmaxf(m_run, tm);
                float scale = __expf(m_run - m_new);
                m_run = m_new;
                l_run *= scale;
                f32x4 scv;
                scv[0] = __shfl(scale, lg * 4 + 0);
                scv[1] = __shfl(scale, lg * 4 + 1);
                scv[2] = __shfl(scale, lg * 4 + 2);
                scv[3] = __shfl(scale, lg * 4 + 3);
                #pragma unroll
                for (int dt = 0; dt < 4; ++dt) accO[dt] *= scv;
            }

            float p[8]; float ps = 0.f;
            #pragma unroll
            for (int i = 0; i < 8; ++i) { p[i] = __expf(sv[i] - m_run); ps += p[i]; }
            ps += __shfl_xor(ps, 16);
            ps += __shfl_xor(ps, 32);
            l_run += ps;

            unsigned dA0 = cvtpk(p[0], p[1]);
            unsigned dA1 = cvtpk(p[2], p[3]);
            unsigned dB0 = cvtpk(p[4], p[5]);
            unsigned dB1 = cvtpk(p[6], p[7]);
            int sl0 = lq + ((lg & 1) << 5);
            int sl1 = sl0 + 16;
            unsigned a0 = (unsigned)__shfl((int)dA0, sl0), a1 = (unsigned)__shfl((int)dA1, sl0);
            unsigned a2 = (unsigned)__shfl((int)dA0, sl1), a3 = (unsigned)__shfl((int)dA1, sl1);
            unsigned c0 = (unsigned)__shfl((int)dB0, sl0), c1 = (unsigned)__shfl((int)dB1, sl0);
            unsigned c2 = (unsigned)__shfl((int)dB0, sl1), c3 = (unsigned)__shfl((int)dB1, sl1);
            bool hi = (lg >= 2);
            union { unsigned u[4]; s16x8 v; } pa;
            pa.u[0] = hi ? c0 : a0; pa.u[1] = hi ? c1 : a1;
            pa.u[2] = hi ? c2 : a2; pa.u[3] = hi ? c3 : a3;

            __builtin_amdgcn_s_setprio(1);
            #pragma unroll
            for (int dt = 0; dt < 4; ++dt) {
                int vrow = dt * 16 + lq;
                int voff = (vrow * 64 + (lg << 4)) ^ ((vrow & 3) << 4);
                accO[dt] = mfma16(pa.v, ldlds(Vs, voff), accO[dt]);
            }
            __builtin_amdgcn_s_setprio(0);
        }

        asm volatile("" ::: "memory");
        __builtin_amdgcn_s_barrier();     // all waves done with Vs + buf[cur]
        if (t + 1 < nslab) STAGE_V((t + 1) * 32);
    }

    float inv = 1.0f / l_run;
    f32x4 invv;
    invv[0] = __shfl(inv, lg * 4 + 0);
    invv[1] = __shfl(inv, lg * 4 + 1);
    invv[2] = __shfl(inv, lg * 4 + 2);
    invv[3] = __shfl(inv, lg * 4 + 3);
    #pragma unroll
    for (int dt = 0; dt < 4; ++dt) {
        #pragma unroll
        for (int r = 0; r < 4; ++r) {
            int qo = q0 + lg * 4 + r;
            size_t off = ((size_t)(b * SEQ + qo)) * DMODEL + h * DHEAD + dt * 16 + lq;
            ctx[off] = f2bf(accO[dt][r] * invv[r]);
        }
    }
}

// ---------------------------------------------------------------------------
extern "C" void kernel_launch(void* const* d_in, const int* in_sizes, int n_in,
                              void* d_out, int out_size, void* d_ws, size_t ws_size,
                              hipStream_t stream) {
    const float* embed = (const float*)d_in[0];
    const int*   umask = (const int*)d_in[1];
    const int*   qmask = (const int*)d_in[2];
    const float* Wqkv  = (const float*)d_in[3];
    const float* Wpos  = (const float*)d_in[4];
    const float* Wfc   = (const float*)d_in[5];
    float* out = (float*)d_out;

    char* w = (char*)d_ws;
    short* qb    = (short*)(w + (0ull  << 20));  // [B][H][L][64]    8 MB
    short* vtb   = (short*)(w + (8ull  << 20));  // [B][H][64][L]    8 MB
    short* qpb   = (short*)(w + (16ull << 20));  // [H][L][64]       2 MB
    short* ctx   = (short*)(w + (18ull << 20));  // [B*L][1024]      8 MB
    short* ebf   = ctx;                          // aliased: ebf dead before attn
    short* k1cat = (short*)(w + (26ull << 20));  // [B][H][L][128]  16 MB
    short* k2cat = (short*)(w + (42ull << 20));  // [B][H][L][128]  16 MB
    int*   PM    = (int*)  (w + (58ull << 20));  // [4][1088]       ~17 KB
    short* WqkvT = (short*)(w + (59ull << 20));  // [4096][1024]     8 MB
    short* WfcT  = (short*)(w + (67ull << 20));  // [1024][1024]     2 MB

    hipLaunchKernelGGL(prep_a_kernel, dim3(3072), dim3(256), 0, stream,
                       embed, Wqkv, ebf, WqkvT);
    hipLaunchKernelGGL(gemm_qkv_fused, dim3(900), dim3(512), 0, stream,
                       ebf, WqkvT, qb, k1cat, k2cat, vtb,
                       qmask, umask, Wpos, Wfc, PM, qpb, WfcT);
    hipLaunchKernelGGL(attn_kernel, dim3(1024), dim3(256), 0, stream,
                       qb, k1cat, k2cat, vtb, qpb, PM, qmask, ctx);
    hipLaunchKernelGGL((gemm_nt<1, 1024>), dim3(8, 32), dim3(256), 0, stream,
                       ctx, WfcT, out);
}

// Round 22
// 155.731 us; speedup vs baseline: 1.0011x; 1.0011x over previous
//
#include <hip/hip_runtime.h>
#include <math.h>

#define NB 4
#define SEQ 1024
#define DMODEL 1024
#define NHEAD 16
#define DHEAD 64

typedef __attribute__((ext_vector_type(8))) short s16x8;
typedef __attribute__((ext_vector_type(4))) short s16x4;
typedef __attribute__((ext_vector_type(4))) float f32x4;

__device__ __forceinline__ short f2bf(float f) {
    union { float f; unsigned u; } x; x.f = f;
    unsigned r = x.u + 0x7fffu + ((x.u >> 16) & 1u);   // RNE
    return (short)(r >> 16);
}

__device__ __forceinline__ unsigned cvtpk(float lo, float hi) {
    unsigned r;
    asm("v_cvt_pk_bf16_f32 %0, %1, %2" : "=v"(r) : "v"(lo), "v"(hi));
    return r;   // lo -> [15:0], hi -> [31:16], RNE
}

__device__ __forceinline__ f32x4 mfma16(s16x8 a, s16x8 b, f32x4 c) {
    return __builtin_amdgcn_mfma_f32_16x16x32_bf16(a, b, c, 0, 0, 0);
}

__device__ __forceinline__ s16x8 cvt8(float4 a, float4 b) {
    s16x8 v;
    v[0] = f2bf(a.x); v[1] = f2bf(a.y); v[2] = f2bf(a.z); v[3] = f2bf(a.w);
    v[4] = f2bf(b.x); v[5] = f2bf(b.y); v[6] = f2bf(b.z); v[7] = f2bf(b.w);
    return v;
}

__device__ __forceinline__ s16x8 ldlds(const short* base, int byteoff) {
    return *(const s16x8*)((const char*)base + byteoff);
}

#define GLDS16(g, l) __builtin_amdgcn_global_load_lds( \
    (const __attribute__((address_space(1))) unsigned int*)(g), \
    (__attribute__((address_space(3))) unsigned int*)(l), 16, 0, 0)
#define GLDS4(g, l) __builtin_amdgcn_global_load_lds( \
    (const __attribute__((address_space(1))) unsigned int*)(g), \
    (__attribute__((address_space(3))) unsigned int*)(l), 4, 0, 0)

// ---------------------------------------------------------------------------
// prep_a: pre-passes gemm1 DEPENDS on.
//   [0,2048)      convert embed fp32 -> bf16 (ebf)
//   [2048,3072)   transpose Wqkv -> WqkvT bf16
// ---------------------------------------------------------------------------
__global__ __launch_bounds__(256) void prep_a_kernel(
    const float* __restrict__ embed, const float* __restrict__ Wqkv,
    short* __restrict__ ebf, short* __restrict__ WqkvT)
{
    __shared__ __align__(16) char smem[9216];
    int gb = blockIdx.x;
    int tid = threadIdx.x;

    if (gb < 2048) {
        int i = (gb * 256 + tid) * 8;
        float4 a = *(const float4*)(embed + i);
        float4 b = *(const float4*)(embed + i + 4);
        *(s16x8*)(ebf + i) = cvt8(a, b);
    } else {
        int t = gb - 2048;                 // 64 x 16 tiles
        int bx = t & 63, by = t >> 6;
        const int N = 4096;
        short (*T)[72] = (short(*)[72])smem;
        int nt = bx * 64, kt = by * 64;
        int kl = tid >> 4;
        int nl = (tid & 15) * 4;
        #pragma unroll
        for (int rr = 0; rr < 4; ++rr) {
            int k = kl + rr * 16;
            float4 v = *(const float4*)(Wqkv + (size_t)(kt + k) * N + nt + nl);
            T[nl + 0][k] = f2bf(v.x);
            T[nl + 1][k] = f2bf(v.y);
            T[nl + 2][k] = f2bf(v.z);
            T[nl + 3][k] = f2bf(v.w);
        }
        __syncthreads();
        int nr = tid >> 2;
        int kc = (tid & 3) * 16;
        uint4 a = *(const uint4*)&T[nr][kc];
        uint4 b = *(const uint4*)&T[nr][kc + 8];
        short* dst = WqkvT + (size_t)(nt + nr) * 1024 + kt + kc;
        *(uint4*)(dst) = a;
        *(uint4*)(dst + 8) = b;
    }
}

// ---------------------------------------------------------------------------
// gemm_qkv_fused: 512-thread blocks, 64KB LDS.
// Blocks [0,256): QKV GEMM 256x256 tile, 8 waves, BK=32, depth-1
//   counted-vmcnt dbuf, 1-D XCD swizzle, scatter epilogue.
//   NEW: LDS swizzle upgraded (row&3 -> (row>>1)&3): among the 8 same-parity
//   rows a ds_read_b128 touches per bank-group, the XOR now cycles all 4
//   16B slots (was 2) -> 2-way bank aliasing (free) instead of 4-way.
//   Source pre-swizzle updated to match: (lane>>3)&3 == (srow>>1)&3.
// Blocks [256,900): prep_b — tail-fill CUs as gemm blocks retire.
//   [0,4) mask_pack; [4,388) pos_proj; [388,644) WfcT transpose
// ---------------------------------------------------------------------------
__global__ __launch_bounds__(512, 2) void gemm_qkv_fused(
    const short* __restrict__ A, const short* __restrict__ BT,
    short* __restrict__ o0, short* __restrict__ o1, short* __restrict__ o2,
    short* __restrict__ o3,
    const int* __restrict__ qmask, const int* __restrict__ umask,
    const float* __restrict__ Wpos, const float* __restrict__ Wfc,
    int* __restrict__ PM, short* __restrict__ qpb, short* __restrict__ WfcT)
{
    __shared__ short As[2][256 * 32];      // 16KB per buffer
    __shared__ short Bs[2][256 * 32];

    int gb = blockIdx.x;
    int tid = threadIdx.x;

    if (gb >= 256) {
        int pb = gb - 256;
        char* smem = (char*)&As[0][0];
        if (pb < 4) {
            // ------- mask_pack -------
            if (tid < 256) {
                int b = pb;
                for (int k = tid; k < 1088; k += 256) {
                    int v = 2;
                    if (k < 1024)
                        v = (qmask[b * 1024 + k] & 1) | ((umask[b * 1024 + k] == 0) ? 2 : 0);
                    PM[b * 1088 + k] = v;
                }
            }
        } else if (pb < 388) {
            // ------- pos_proj -------
            int bid = pb - 4;
            int s = bid >> 7;
            int l0 = (bid & 127) * 8;
            float (*pe)[64] = (float(*)[64])smem;

            if (tid < 256) {
                for (int idx = tid; idx < 512; idx += 256) {
                    int li = idx >> 6, t = idx & 63;
                    float p = (float)(l0 + li - 512);
                    int j = (t < 32) ? t : (t - 32);
                    float f = expf(-0.2971077539f * (float)j);   // ln(10000)/31
                    float a = p * f;
                    pe[li][t] = (t < 32) ? sinf(a) : cosf(a);
                }
            }
            __syncthreads();

            if (tid < 256) {
                float acc[4][8] = {};
                const float* wp = Wpos + s * 1024 + tid;
                for (int t = 0; t < 64; ++t) {
                    float w0 = wp[t * 3072];
                    float w1 = wp[t * 3072 + 256];
                    float w2 = wp[t * 3072 + 512];
                    float w3 = wp[t * 3072 + 768];
                    #pragma unroll
                    for (int li = 0; li < 8; ++li) {
                        float pv = pe[li][t];
                        acc[0][li] += pv * w0; acc[1][li] += pv * w1;
                        acc[2][li] += pv * w2; acc[3][li] += pv * w3;
                    }
                }
                #pragma unroll
                for (int cc = 0; cc < 4; ++cc) {
                    int c = tid + cc * 256;
                    int h = c >> 6, d = c & 63;
                    #pragma unroll
                    for (int li = 0; li < 8; ++li) {
                        short bv = f2bf(acc[cc][li]);
                        if (s == 0) {
                            qpb[((size_t)(h << 10) + l0 + li) * 64 + d] = bv;
                        } else {
                            short* dst = (s == 1) ? o1 : o2;   // k1cat / k2cat
                            #pragma unroll
                            for (int bb = 0; bb < 4; ++bb)
                                dst[((size_t)((bb * 16 + h) * 1024) + l0 + li) * 128 + 64 + d] = bv;
                        }
                    }
                }
            }
        } else {
            // ------- WfcT transpose -------
            int t = pb - 388;              // 16 x 16 tiles
            int bx = t & 15, by = t >> 4;
            const int N = 1024;
            short (*T)[72] = (short(*)[72])smem;
            int nt = bx * 64, kt = by * 64;
            if (tid < 256) {
                int kl = tid >> 4;
                int nl = (tid & 15) * 4;
                #pragma unroll
                for (int rr = 0; rr < 4; ++rr) {
                    int k = kl + rr * 16;
                    float4 v = *(const float4*)(Wfc + (size_t)(kt + k) * N + nt + nl);
                    T[nl + 0][k] = f2bf(v.x);
                    T[nl + 1][k] = f2bf(v.y);
                    T[nl + 2][k] = f2bf(v.z);
                    T[nl + 3][k] = f2bf(v.w);
                }
            }
            __syncthreads();
            if (tid < 256) {
                int nr = tid >> 2;
                int kc = (tid & 3) * 16;
                uint4 a = *(const uint4*)&T[nr][kc];
                uint4 b = *(const uint4*)&T[nr][kc + 8];
                short* dst = WfcT + (size_t)(nt + nr) * 1024 + kt + kc;
                *(uint4*)(dst) = a;
                *(uint4*)(dst + 8) = b;
            }
        }
        return;
    }

    // ------------------- QKV GEMM: 256^2 tile, 8 waves, depth-1 -----------
    int lin = gb;                          // 0..255
    int swb = (lin & 7) * 32 + (lin >> 3); // 1-D XCD swizzle (bijective)
    int bx = swb & 15, by = swb >> 4;      // grid 16 x 16
    int m0 = by * 256, n0 = bx * 256;

    int w = tid >> 6, lane = tid & 63;     // w in [0,8)
    int wm = w >> 2, wn = w & 3;           // 2 x 4 wave grid
    int lq = lane & 15, lg = lane >> 4;

    f32x4 zero = {0.f, 0.f, 0.f, 0.f};
    f32x4 acc[8][4];
    #pragma unroll
    for (int i = 0; i < 8; ++i)
        #pragma unroll
        for (int jj = 0; jj < 4; ++jj) acc[i][jj] = zero;

    int swz = (((lane & 3) ^ ((lane >> 3) & 3)) << 3);   // (srow>>1)&3 pre-swizzle
    int srow = lane >> 2;
    const short* aBase = A  + (size_t)(m0 + (w << 5) + srow) * 1024 + swz;
    const short* bBase = BT + (size_t)(n0 + (w << 5) + srow) * 1024 + swz;
    int dOff = w * 1024;                   // wave region: 32 rows x 32 shorts

    GLDS16(aBase, &As[0][dOff]);
    GLDS16(aBase + 16 * 1024, &As[0][dOff + 512]);
    GLDS16(bBase, &Bs[0][dOff]);
    GLDS16(bBase + 16 * 1024, &Bs[0][dOff + 512]);

    int cur = 0;
    for (int kt = 0; kt < 1024; kt += 32) {
        if (kt + 32 < 1024) {
            int nxt = cur ^ 1;
            GLDS16(aBase + kt + 32, &As[nxt][dOff]);
            GLDS16(aBase + kt + 32 + 16 * 1024, &As[nxt][dOff + 512]);
            GLDS16(bBase + kt + 32, &Bs[nxt][dOff]);
            GLDS16(bBase + kt + 32 + 16 * 1024, &Bs[nxt][dOff + 512]);
            asm volatile("s_waitcnt vmcnt(4)" ::: "memory");
        } else {
            asm volatile("s_waitcnt vmcnt(0)" ::: "memory");
        }
        __builtin_amdgcn_s_barrier();      // all waves: tile kt resident
        asm volatile("" ::: "memory");

        s16x8 bfr[4];
        #pragma unroll
        for (int nt = 0; nt < 4; ++nt) {
            int row = wn * 64 + nt * 16 + lq;
            bfr[nt] = ldlds(Bs[cur], (row * 64 + lg * 16) ^ (((row >> 1) & 3) << 4));
        }
        #pragma unroll
        for (int mt = 0; mt < 8; ++mt) {
            int row = wm * 128 + mt * 16 + lq;
            s16x8 af = ldlds(As[cur], (row * 64 + lg * 16) ^ (((row >> 1) & 3) << 4));
            #pragma unroll
            for (int nt = 0; nt < 4; ++nt)
                acc[mt][nt] = mfma16(af, bfr[nt], acc[mt][nt]);
        }

        asm volatile("" ::: "memory");
        __builtin_amdgcn_s_barrier();      // buf[cur] free for overwrite
        cur ^= 1;
    }

    // scatter epilogue (128x64 per wave)
    #pragma unroll
    for (int nt = 0; nt < 4; ++nt) {
        int n = n0 + wn * 64 + nt * 16 + lq;
        int sec = n >> 10, hd = n & 1023;
        int hh = hd >> 6, d = hd & 63;
        #pragma unroll
        for (int mt = 0; mt < 8; ++mt) {
            int mb = m0 + wm * 128 + mt * 16 + lg * 4;
            int b = mb >> 10, li0 = mb & 1023;
            int bh = b * 16 + hh;
            if (sec == 3) {
                s16x4 pv;
                #pragma unroll
                for (int r = 0; r < 4; ++r) pv[r] = f2bf(acc[mt][nt][r]);
                *(s16x4*)(o3 + (((size_t)(bh * 64 + d)) << 10) + li0) = pv;
            } else {
                #pragma unroll
                for (int r = 0; r < 4; ++r) {
                    short bv = f2bf(acc[mt][nt][r]);
                    if (sec == 0)
                        o0[((size_t)(bh << 10) + li0 + r) * 64 + d] = bv;
                    else if (sec == 1)
                        o1[((size_t)bh * 1024 + li0 + r) * 128 + d] = bv;
                    else
                        o2[((size_t)bh * 1024 + li0 + r) * 128 + d] = bv;
                }
            }
        }
    }
}

// ---------------------------------------------------------------------------
// gemm_nt (EPI==1 only): final projection ctx @ WfcT -> out fp32.
// R8 structure: depth-1 counted-vmcnt dbuf, 1-D XCD swizzle; same upgraded
// (row>>1)&3 LDS swizzle as gemm1.
// ---------------------------------------------------------------------------
template<int EPI, int NCOLS>
__global__ __launch_bounds__(256) void gemm_nt(
    const short* __restrict__ A, const short* __restrict__ BT,
    float* __restrict__ of)
{
    __shared__ short As[2][128 * 32];
    __shared__ short Bs[2][128 * 32];

    int nwg = gridDim.x * gridDim.y;
    int lin = blockIdx.y * gridDim.x + blockIdx.x;
    int cpx = nwg >> 3;
    int swb = (lin & 7) * cpx + (lin >> 3);
    int bx = swb % gridDim.x, by = swb / gridDim.x;
    int m0 = by * 128, n0 = bx * 128;

    int tid = threadIdx.x;
    int w = tid >> 6, lane = tid & 63;
    int wm = w >> 1, wn = w & 1;
    int lq = lane & 15, lg = lane >> 4;

    f32x4 zero = {0.f, 0.f, 0.f, 0.f};
    f32x4 acc[4][4];
    #pragma unroll
    for (int i = 0; i < 4; ++i)
        #pragma unroll
        for (int j = 0; j < 4; ++j) acc[i][j] = zero;

    int swz = (((lane & 3) ^ ((lane >> 3) & 3)) << 3);   // (srow>>1)&3 pre-swizzle
    int srow = lane >> 2;
    const short* aBase = A  + (size_t)(m0 + (w << 5) + srow) * 1024 + swz;
    const short* bBase = BT + (size_t)(n0 + (w << 5) + srow) * 1024 + swz;
    int dOff = w * 1024;

    GLDS16(aBase, &As[0][dOff]);
    GLDS16(aBase + 16 * 1024, &As[0][dOff + 512]);
    GLDS16(bBase, &Bs[0][dOff]);
    GLDS16(bBase + 16 * 1024, &Bs[0][dOff + 512]);

    int cur = 0;
    for (int kt = 0; kt < 1024; kt += 32) {
        if (kt + 32 < 1024) {
            int nxt = cur ^ 1;
            GLDS16(aBase + kt + 32, &As[nxt][dOff]);
            GLDS16(aBase + kt + 32 + 16 * 1024, &As[nxt][dOff + 512]);
            GLDS16(bBase + kt + 32, &Bs[nxt][dOff]);
            GLDS16(bBase + kt + 32 + 16 * 1024, &Bs[nxt][dOff + 512]);
            asm volatile("s_waitcnt vmcnt(4)" ::: "memory");
        } else {
            asm volatile("s_waitcnt vmcnt(0)" ::: "memory");
        }
        __builtin_amdgcn_s_barrier();
        asm volatile("" ::: "memory");

        s16x8 af[4], bfr[4];
        #pragma unroll
        for (int mt = 0; mt < 4; ++mt) {
            int row = wm * 64 + mt * 16 + lq;
            af[mt] = ldlds(As[cur], (row * 64 + lg * 16) ^ (((row >> 1) & 3) << 4));
        }
        #pragma unroll
        for (int nt = 0; nt < 4; ++nt) {
            int row = wn * 64 + nt * 16 + lq;
            bfr[nt] = ldlds(Bs[cur], (row * 64 + lg * 16) ^ (((row >> 1) & 3) << 4));
        }
        #pragma unroll
        for (int mt = 0; mt < 4; ++mt)
            #pragma unroll
            for (int nt = 0; nt < 4; ++nt)
                acc[mt][nt] = mfma16(af[mt], bfr[nt], acc[mt][nt]);

        asm volatile("" ::: "memory");
        __builtin_amdgcn_s_barrier();
        cur ^= 1;
    }

    #pragma unroll
    for (int nt = 0; nt < 4; ++nt) {
        int n = n0 + wn * 64 + nt * 16 + lq;
        #pragma unroll
        for (int mt = 0; mt < 4; ++mt) {
            int mb = m0 + wm * 64 + mt * 16 + lg * 4;
            #pragma unroll
            for (int r = 0; r < 4; ++r)
                of[(size_t)(mb + r) * NCOLS + n] = acc[mt][nt][r];
        }
    }
}

// ---------------------------------------------------------------------------
// attn: flash attention (best measured, 64.9 us): grid 1024 = 64 bh x
// 16 q-tiles, bh = xg*8+(j&7) / qt = 15-(j>>3) (load-balance-optimal map);
// K double-buffered via counted vmcnt; V single-buffered staged at loop
// bottom; defer-max, cvt_pk, setprio, b128 mask reads. (256B rows already
// have a 2-way-optimal (row&7)<<4 swizzle — unchanged.)
// ---------------------------------------------------------------------------
__global__ __launch_bounds__(256) void attn_kernel(
    const short* __restrict__ qb, const short* __restrict__ k1cat,
    const short* __restrict__ k2cat, const short* __restrict__ vtb,
    const short* __restrict__ qpb, const int* __restrict__ PM,
    const int* __restrict__ qmask, short* __restrict__ ctx)
{
    __shared__ short K1s[2][32 * 128];
    __shared__ short K2s[2][32 * 128];
    __shared__ short Vs[64 * 32];         // single buffer (staged post-barrier)
    __shared__ int   PMs[2][64];

    int bid = blockIdx.x;                 // 1024 blocks
    int xg = bid & 7, j = bid >> 3;       // xg = XCD, j in [0,128)
    int bh = xg * 8 + (j & 7);            // 8 bh panels per XCD (L2 reuse)
    int qt = 15 - (j >> 3);               // descending qt: big blocks first
    int b = bh >> 4, h = bh & 15;

    int w = threadIdx.x >> 6, lane = threadIdx.x & 63;
    int lq = lane & 15, lg = lane >> 4;

    auto STAGE_K = [&](int d, int K0) {
        #pragma unroll
        for (int i = 0; i < 4; ++i) {
            int g = w * 4 + i;
            if (g < 8) {
                int row = g * 4 + (lane >> 4);
                int colb = ((lane & 15) << 4) ^ ((row & 7) << 4);
                const short* src = k1cat + ((size_t)bh * 1024 + K0 + row) * 128 + (colb >> 1);
                GLDS16(src, &K1s[d][g * 512]);
            } else {
                int gg = g - 8;
                int row = gg * 4 + (lane >> 4);
                int colb = ((lane & 15) << 4) ^ ((row & 7) << 4);
                const short* src = k2cat + ((size_t)bh * 1024 + K0 + row) * 128 + (colb >> 1);
                GLDS16(src, &K2s[d][gg * 512]);
            }
        }
        if (w == 0) {
            GLDS4(PM + b * 1088 + K0 + lane, &PMs[d][0]);
        }
    };
    auto STAGE_V = [&](int K0) {
        int row = w * 16 + (lane >> 2);
        int colb = ((lane & 3) << 4) ^ ((row & 3) << 4);
        const short* src = vtb + ((size_t)bh * 64 + row) * 1024 + K0 + (colb >> 1);
        GLDS16(src, &Vs[w * 512]);
    };

    f32x4 zero = {0.f, 0.f, 0.f, 0.f};

    int q0 = qt * 64 + w * 16;
    int q_glob = q0 + lq;

    const short* qrow  = qb  + ((size_t)bh * SEQ + q_glob) * DHEAD;
    const short* qprow = qpb + ((size_t)h  * SEQ + q_glob) * DHEAD;
    s16x8 qf0  = *(const s16x8*)(qrow + lg * 8);
    s16x8 qf1  = *(const s16x8*)(qrow + 32 + lg * 8);
    s16x8 qpf0 = *(const s16x8*)(qprow + lg * 8);
    s16x8 qpf1 = *(const s16x8*)(qprow + 32 + lg * 8);
    int qm_q = qmask[b * SEQ + q_glob] & 1;
    asm volatile("s_waitcnt vmcnt(0)" ::: "memory");

    f32x4 accO[4];
    #pragma unroll
    for (int i = 0; i < 4; ++i) accO[i] = zero;
    float m_run = -1e30f, l_run = 0.f;

    int nslab = 2 * qt + 2;
    STAGE_K(0, 0);
    STAGE_V(0);

    #pragma unroll 1
    for (int t = 0; t < nslab; ++t) {
        int cur = t & 1;
        if (t + 1 < nslab) {
            STAGE_K(cur ^ 1, (t + 1) * 32);
            if (w == 0) asm volatile("s_waitcnt vmcnt(5)" ::: "memory");
            else        asm volatile("s_waitcnt vmcnt(4)" ::: "memory");
        } else {
            asm volatile("s_waitcnt vmcnt(0)" ::: "memory");
        }
        __builtin_amdgcn_s_barrier();
        asm volatile("" ::: "memory");

        int K0 = t * 32;
        if (K0 <= q0 + 15) {
            const short* b1 = K1s[cur];
            const short* b2 = K2s[cur];

            f32x4 s1v[2], s2v[2];
            __builtin_amdgcn_s_setprio(1);
            #pragma unroll
            for (int hh = 0; hh < 2; ++hh) {
                int row = hh * 16 + lq;
                int ro = row * 256 + (lg << 4);
                int sw = (row & 7) << 4;
                f32x4 tv = zero, uv = zero;
                tv = mfma16(ldlds(b1, (ro      ) ^ sw), qf0,  tv);
                tv = mfma16(ldlds(b1, (ro +  64) ^ sw), qf1,  tv);
                tv = mfma16(ldlds(b1, (ro + 128) ^ sw), qpf0, tv);
                tv = mfma16(ldlds(b1, (ro + 192) ^ sw), qpf1, tv);
                s1v[hh] = tv;
                uv = mfma16(ldlds(b2, (ro      ) ^ sw), qf0,  uv);
                uv = mfma16(ldlds(b2, (ro +  64) ^ sw), qf1,  uv);
                uv = mfma16(ldlds(b2, (ro + 128) ^ sw), qpf0, uv);
                uv = mfma16(ldlds(b2, (ro + 192) ^ sw), qpf1, uv);
                s2v[hh] = uv;
            }
            __builtin_amdgcn_s_setprio(0);

            int4 pmv0 = *(const int4*)&PMs[cur][lg * 4];
            int4 pmv1 = *(const int4*)&PMs[cur][16 + lg * 4];
            int pme[8] = {pmv0.x, pmv0.y, pmv0.z, pmv0.w,
                          pmv1.x, pmv1.y, pmv1.z, pmv1.w};

            float sv[8];
            #pragma unroll
            for (int i = 0; i < 8; ++i) {
                int hh = i >> 2, r = i & 3;
                int k_idx = K0 + hh * 16 + lg * 4 + r;
                int pm = pme[i];
                float s = ((pm & 1) == qm_q) ? s1v[hh][r] : s2v[hh][r];
                if (k_idx > q_glob || (pm & 2)) s = -INFINITY;
                sv[i] = s;
            }
            float tm = sv[0];
            #pragma unroll
            for (int i = 1; i < 8; ++i) tm = fmaxf(tm, sv[i]);
            tm = fmaxf(tm, __shfl_xor(tm, 16));
            tm = fmaxf(tm, __shfl_xor(tm, 32));

            if (!__all(tm <= m_run + 8.0f)) {
                float m_new = fmaxf(m_run, tm);
                float scale = __expf(m_run - m_new);
                m_run = m_new;
                l_run *= scale;
                f32x4 scv;
                scv[0] = __shfl(scale, lg * 4 + 0);
                scv[1] = __shfl(scale, lg * 4 + 1);
                scv[2] = __shfl(scale, lg * 4 + 2);
                scv[3] = __shfl(scale, lg * 4 + 3);
                #pragma unroll
                for (int dt = 0; dt < 4; ++dt) accO[dt] *= scv;
            }

            float p[8]; float ps = 0.f;
            #pragma unroll
            for (int i = 0; i < 8; ++i) { p[i] = __expf(sv[i] - m_run); ps += p[i]; }
            ps += __shfl_xor(ps, 16);
            ps += __shfl_xor(ps, 32);
            l_run += ps;

            unsigned dA0 = cvtpk(p[0], p[1]);
            unsigned dA1 = cvtpk(p[2], p[3]);
            unsigned dB0 = cvtpk(p[4], p[5]);
            unsigned dB1 = cvtpk(p[6], p[7]);
            int sl0 = lq + ((lg & 1) << 5);
            int sl1 = sl0 + 16;
            unsigned a0 = (unsigned)__shfl((int)dA0, sl0), a1 = (unsigned)__shfl((int)dA1, sl0);
            unsigned a2 = (unsigned)__shfl((int)dA0, sl1), a3 = (unsigned)__shfl((int)dA1, sl1);
            unsigned c0 = (unsigned)__shfl((int)dB0, sl0), c1 = (unsigned)__shfl((int)dB1, sl0);
            unsigned c2 = (unsigned)__shfl((int)dB0, sl1), c3 = (unsigned)__shfl((int)dB1, sl1);
            bool hi = (lg >= 2);
            union { unsigned u[4]; s16x8 v; } pa;
            pa.u[0] = hi ? c0 : a0; pa.u[1] = hi ? c1 : a1;
            pa.u[2] = hi ? c2 : a2; pa.u[3] = hi ? c3 : a3;

            __builtin_amdgcn_s_setprio(1);
            #pragma unroll
            for (int dt = 0; dt < 4; ++dt) {
                int vrow = dt * 16 + lq;
                int voff = (vrow * 64 + (lg << 4)) ^ ((vrow & 3) << 4);
                accO[dt] = mfma16(pa.v, ldlds(Vs, voff), accO[dt]);
            }
            __builtin_amdgcn_s_setprio(0);
        }

        asm volatile("" ::: "memory");
        __builtin_amdgcn_s_barrier();     // all waves done with Vs + buf[cur]
        if (t + 1 < nslab) STAGE_V((t + 1) * 32);
    }

    float inv = 1.0f / l_run;
    f32x4 invv;
    invv[0] = __shfl(inv, lg * 4 + 0);
    invv[1] = __shfl(inv, lg * 4 + 1);
    invv[2] = __shfl(inv, lg * 4 + 2);
    invv[3] = __shfl(inv, lg * 4 + 3);
    #pragma unroll
    for (int dt = 0; dt < 4; ++dt) {
        #pragma unroll
        for (int r = 0; r < 4; ++r) {
            int qo = q0 + lg * 4 + r;
            size_t off = ((size_t)(b * SEQ + qo)) * DMODEL + h * DHEAD + dt * 16 + lq;
            ctx[off] = f2bf(accO[dt][r] * invv[r]);
        }
    }
}

// ---------------------------------------------------------------------------
extern "C" void kernel_launch(void* const* d_in, const int* in_sizes, int n_in,
                              void* d_out, int out_size, void* d_ws, size_t ws_size,
                              hipStream_t stream) {
    const float* embed = (const float*)d_in[0];
    const int*   umask = (const int*)d_in[1];
    const int*   qmask = (const int*)d_in[2];
    const float* Wqkv  = (const float*)d_in[3];
    const float* Wpos  = (const float*)d_in[4];
    const float* Wfc   = (const float*)d_in[5];
    float* out = (float*)d_out;

    char* w = (char*)d_ws;
    short* qb    = (short*)(w + (0ull  << 20));  // [B][H][L][64]    8 MB
    short* vtb   = (short*)(w + (8ull  << 20));  // [B][H][64][L]    8 MB
    short* qpb   = (short*)(w + (16ull << 20));  // [H][L][64]       2 MB
    short* ctx   = (short*)(w + (18ull << 20));  // [B*L][1024]      8 MB
    short* ebf   = ctx;                          // aliased: ebf dead before attn
    short* k1cat = (short*)(w + (26ull << 20));  // [B][H][L][128]  16 MB
    short* k2cat = (short*)(w + (42ull << 20));  // [B][H][L][128]  16 MB
    int*   PM    = (int*)  (w + (58ull << 20));  // [4][1088]       ~17 KB
    short* WqkvT = (short*)(w + (59ull << 20));  // [4096][1024]     8 MB
    short* WfcT  = (short*)(w + (67ull << 20));  // [1024][1024]     2 MB

    hipLaunchKernelGGL(prep_a_kernel, dim3(3072), dim3(256), 0, stream,
                       embed, Wqkv, ebf, WqkvT);
    hipLaunchKernelGGL(gemm_qkv_fused, dim3(900), dim3(512), 0, stream,
                       ebf, WqkvT, qb, k1cat, k2cat, vtb,
                       qmask, umask, Wpos, Wfc, PM, qpb, WfcT);
    hipLaunchKernelGGL(attn_kernel, dim3(1024), dim3(256), 0, stream,
                       qb, k1cat, k2cat, vtb, qpb, PM, qmask, ctx);
    hipLaunchKernelGGL((gemm_nt<1, 1024>), dim3(8, 32), dim3(256), 0, stream,
                       ctx, WfcT, out);
}

// Round 23
// 155.115 us; speedup vs baseline: 1.0051x; 1.0040x over previous
//
#include <hip/hip_runtime.h>
#include <math.h>

#define NB 4
#define SEQ 1024
#define DMODEL 1024
#define NHEAD 16
#define DHEAD 64

typedef __attribute__((ext_vector_type(8))) short s16x8;
typedef __attribute__((ext_vector_type(4))) short s16x4;
typedef __attribute__((ext_vector_type(4))) float f32x4;

__device__ __forceinline__ short f2bf(float f) {
    union { float f; unsigned u; } x; x.f = f;
    unsigned r = x.u + 0x7fffu + ((x.u >> 16) & 1u);   // RNE
    return (short)(r >> 16);
}

__device__ __forceinline__ unsigned cvtpk(float lo, float hi) {
    unsigned r;
    asm("v_cvt_pk_bf16_f32 %0, %1, %2" : "=v"(r) : "v"(lo), "v"(hi));
    return r;   // lo -> [15:0], hi -> [31:16], RNE
}

__device__ __forceinline__ f32x4 mfma16(s16x8 a, s16x8 b, f32x4 c) {
    return __builtin_amdgcn_mfma_f32_16x16x32_bf16(a, b, c, 0, 0, 0);
}

__device__ __forceinline__ s16x8 cvt8(float4 a, float4 b) {
    s16x8 v;
    v[0] = f2bf(a.x); v[1] = f2bf(a.y); v[2] = f2bf(a.z); v[3] = f2bf(a.w);
    v[4] = f2bf(b.x); v[5] = f2bf(b.y); v[6] = f2bf(b.z); v[7] = f2bf(b.w);
    return v;
}

__device__ __forceinline__ s16x8 ldlds(const short* base, int byteoff) {
    return *(const s16x8*)((const char*)base + byteoff);
}

#define GLDS16(g, l) __builtin_amdgcn_global_load_lds( \
    (const __attribute__((address_space(1))) unsigned int*)(g), \
    (__attribute__((address_space(3))) unsigned int*)(l), 16, 0, 0)
#define GLDS4(g, l) __builtin_amdgcn_global_load_lds( \
    (const __attribute__((address_space(1))) unsigned int*)(g), \
    (__attribute__((address_space(3))) unsigned int*)(l), 4, 0, 0)

// ---------------------------------------------------------------------------
// prep_a: pre-passes gemm1 DEPENDS on.
//   [0,2048)      convert embed fp32 -> bf16 (ebf)
//   [2048,3072)   transpose Wqkv -> WqkvT bf16
// ---------------------------------------------------------------------------
__global__ __launch_bounds__(256) void prep_a_kernel(
    const float* __restrict__ embed, const float* __restrict__ Wqkv,
    short* __restrict__ ebf, short* __restrict__ WqkvT)
{
    __shared__ __align__(16) char smem[9216];
    int gb = blockIdx.x;
    int tid = threadIdx.x;

    if (gb < 2048) {
        int i = (gb * 256 + tid) * 8;
        float4 a = *(const float4*)(embed + i);
        float4 b = *(const float4*)(embed + i + 4);
        *(s16x8*)(ebf + i) = cvt8(a, b);
    } else {
        int t = gb - 2048;                 // 64 x 16 tiles
        int bx = t & 63, by = t >> 6;
        const int N = 4096;
        short (*T)[72] = (short(*)[72])smem;
        int nt = bx * 64, kt = by * 64;
        int kl = tid >> 4;
        int nl = (tid & 15) * 4;
        #pragma unroll
        for (int rr = 0; rr < 4; ++rr) {
            int k = kl + rr * 16;
            float4 v = *(const float4*)(Wqkv + (size_t)(kt + k) * N + nt + nl);
            T[nl + 0][k] = f2bf(v.x);
            T[nl + 1][k] = f2bf(v.y);
            T[nl + 2][k] = f2bf(v.z);
            T[nl + 3][k] = f2bf(v.w);
        }
        __syncthreads();
        int nr = tid >> 2;
        int kc = (tid & 3) * 16;
        uint4 a = *(const uint4*)&T[nr][kc];
        uint4 b = *(const uint4*)&T[nr][kc + 8];
        short* dst = WqkvT + (size_t)(nt + nr) * 1024 + kt + kc;
        *(uint4*)(dst) = a;
        *(uint4*)(dst + 8) = b;
    }
}

// ---------------------------------------------------------------------------
// gemm_qkv_fused: 512-thread blocks, 64KB LDS.
// Blocks [0,256): QKV GEMM 256x256 tile, 8 waves, BK=32, depth-1
//   counted-vmcnt dbuf, 1-D XCD swizzle, (row>>1)&3 LDS swizzle (2-way
//   aliasing, bank-conflict-free per R22 counters), scatter epilogue.
// Blocks [256,900): prep_b — tail-fill CUs as gemm blocks retire.
//   [0,4) mask_pack; [4,388) pos_proj; [388,644) WfcT transpose
// ---------------------------------------------------------------------------
__global__ __launch_bounds__(512, 2) void gemm_qkv_fused(
    const short* __restrict__ A, const short* __restrict__ BT,
    short* __restrict__ o0, short* __restrict__ o1, short* __restrict__ o2,
    short* __restrict__ o3,
    const int* __restrict__ qmask, const int* __restrict__ umask,
    const float* __restrict__ Wpos, const float* __restrict__ Wfc,
    int* __restrict__ PM, short* __restrict__ qpb, short* __restrict__ WfcT)
{
    __shared__ short As[2][256 * 32];      // 16KB per buffer
    __shared__ short Bs[2][256 * 32];

    int gb = blockIdx.x;
    int tid = threadIdx.x;

    if (gb >= 256) {
        int pb = gb - 256;
        char* smem = (char*)&As[0][0];
        if (pb < 4) {
            // ------- mask_pack -------
            if (tid < 256) {
                int b = pb;
                for (int k = tid; k < 1088; k += 256) {
                    int v = 2;
                    if (k < 1024)
                        v = (qmask[b * 1024 + k] & 1) | ((umask[b * 1024 + k] == 0) ? 2 : 0);
                    PM[b * 1088 + k] = v;
                }
            }
        } else if (pb < 388) {
            // ------- pos_proj -------
            int bid = pb - 4;
            int s = bid >> 7;
            int l0 = (bid & 127) * 8;
            float (*pe)[64] = (float(*)[64])smem;

            if (tid < 256) {
                for (int idx = tid; idx < 512; idx += 256) {
                    int li = idx >> 6, t = idx & 63;
                    float p = (float)(l0 + li - 512);
                    int j = (t < 32) ? t : (t - 32);
                    float f = expf(-0.2971077539f * (float)j);   // ln(10000)/31
                    float a = p * f;
                    pe[li][t] = (t < 32) ? sinf(a) : cosf(a);
                }
            }
            __syncthreads();

            if (tid < 256) {
                float acc[4][8] = {};
                const float* wp = Wpos + s * 1024 + tid;
                for (int t = 0; t < 64; ++t) {
                    float w0 = wp[t * 3072];
                    float w1 = wp[t * 3072 + 256];
                    float w2 = wp[t * 3072 + 512];
                    float w3 = wp[t * 3072 + 768];
                    #pragma unroll
                    for (int li = 0; li < 8; ++li) {
                        float pv = pe[li][t];
                        acc[0][li] += pv * w0; acc[1][li] += pv * w1;
                        acc[2][li] += pv * w2; acc[3][li] += pv * w3;
                    }
                }
                #pragma unroll
                for (int cc = 0; cc < 4; ++cc) {
                    int c = tid + cc * 256;
                    int h = c >> 6, d = c & 63;
                    #pragma unroll
                    for (int li = 0; li < 8; ++li) {
                        short bv = f2bf(acc[cc][li]);
                        if (s == 0) {
                            qpb[((size_t)(h << 10) + l0 + li) * 64 + d] = bv;
                        } else {
                            short* dst = (s == 1) ? o1 : o2;   // k1cat / k2cat
                            #pragma unroll
                            for (int bb = 0; bb < 4; ++bb)
                                dst[((size_t)((bb * 16 + h) * 1024) + l0 + li) * 128 + 64 + d] = bv;
                        }
                    }
                }
            }
        } else {
            // ------- WfcT transpose -------
            int t = pb - 388;              // 16 x 16 tiles
            int bx = t & 15, by = t >> 4;
            const int N = 1024;
            short (*T)[72] = (short(*)[72])smem;
            int nt = bx * 64, kt = by * 64;
            if (tid < 256) {
                int kl = tid >> 4;
                int nl = (tid & 15) * 4;
                #pragma unroll
                for (int rr = 0; rr < 4; ++rr) {
                    int k = kl + rr * 16;
                    float4 v = *(const float4*)(Wfc + (size_t)(kt + k) * N + nt + nl);
                    T[nl + 0][k] = f2bf(v.x);
                    T[nl + 1][k] = f2bf(v.y);
                    T[nl + 2][k] = f2bf(v.z);
                    T[nl + 3][k] = f2bf(v.w);
                }
            }
            __syncthreads();
            if (tid < 256) {
                int nr = tid >> 2;
                int kc = (tid & 3) * 16;
                uint4 a = *(const uint4*)&T[nr][kc];
                uint4 b = *(const uint4*)&T[nr][kc + 8];
                short* dst = WfcT + (size_t)(nt + nr) * 1024 + kt + kc;
                *(uint4*)(dst) = a;
                *(uint4*)(dst + 8) = b;
            }
        }
        return;
    }

    // ------------------- QKV GEMM: 256^2 tile, 8 waves, depth-1 -----------
    int lin = gb;                          // 0..255
    int swb = (lin & 7) * 32 + (lin >> 3); // 1-D XCD swizzle (bijective)
    int bx = swb & 15, by = swb >> 4;      // grid 16 x 16
    int m0 = by * 256, n0 = bx * 256;

    int w = tid >> 6, lane = tid & 63;     // w in [0,8)
    int wm = w >> 2, wn = w & 3;           // 2 x 4 wave grid
    int lq = lane & 15, lg = lane >> 4;

    f32x4 zero = {0.f, 0.f, 0.f, 0.f};
    f32x4 acc[8][4];
    #pragma unroll
    for (int i = 0; i < 8; ++i)
        #pragma unroll
        for (int jj = 0; jj < 4; ++jj) acc[i][jj] = zero;

    int swz = (((lane & 3) ^ ((lane >> 3) & 3)) << 3);   // (srow>>1)&3 pre-swizzle
    int srow = lane >> 2;
    const short* aBase = A  + (size_t)(m0 + (w << 5) + srow) * 1024 + swz;
    const short* bBase = BT + (size_t)(n0 + (w << 5) + srow) * 1024 + swz;
    int dOff = w * 1024;                   // wave region: 32 rows x 32 shorts

    GLDS16(aBase, &As[0][dOff]);
    GLDS16(aBase + 16 * 1024, &As[0][dOff + 512]);
    GLDS16(bBase, &Bs[0][dOff]);
    GLDS16(bBase + 16 * 1024, &Bs[0][dOff + 512]);

    int cur = 0;
    for (int kt = 0; kt < 1024; kt += 32) {
        if (kt + 32 < 1024) {
            int nxt = cur ^ 1;
            GLDS16(aBase + kt + 32, &As[nxt][dOff]);
            GLDS16(aBase + kt + 32 + 16 * 1024, &As[nxt][dOff + 512]);
            GLDS16(bBase + kt + 32, &Bs[nxt][dOff]);
            GLDS16(bBase + kt + 32 + 16 * 1024, &Bs[nxt][dOff + 512]);
            asm volatile("s_waitcnt vmcnt(4)" ::: "memory");
        } else {
            asm volatile("s_waitcnt vmcnt(0)" ::: "memory");
        }
        __builtin_amdgcn_s_barrier();      // all waves: tile kt resident
        asm volatile("" ::: "memory");

        s16x8 bfr[4];
        #pragma unroll
        for (int nt = 0; nt < 4; ++nt) {
            int row = wn * 64 + nt * 16 + lq;
            bfr[nt] = ldlds(Bs[cur], (row * 64 + lg * 16) ^ (((row >> 1) & 3) << 4));
        }
        #pragma unroll
        for (int mt = 0; mt < 8; ++mt) {
            int row = wm * 128 + mt * 16 + lq;
            s16x8 af = ldlds(As[cur], (row * 64 + lg * 16) ^ (((row >> 1) & 3) << 4));
            #pragma unroll
            for (int nt = 0; nt < 4; ++nt)
                acc[mt][nt] = mfma16(af, bfr[nt], acc[mt][nt]);
        }

        asm volatile("" ::: "memory");
        __builtin_amdgcn_s_barrier();      // buf[cur] free for overwrite
        cur ^= 1;
    }

    // scatter epilogue (128x64 per wave)
    #pragma unroll
    for (int nt = 0; nt < 4; ++nt) {
        int n = n0 + wn * 64 + nt * 16 + lq;
        int sec = n >> 10, hd = n & 1023;
        int hh = hd >> 6, d = hd & 63;
        #pragma unroll
        for (int mt = 0; mt < 8; ++mt) {
            int mb = m0 + wm * 128 + mt * 16 + lg * 4;
            int b = mb >> 10, li0 = mb & 1023;
            int bh = b * 16 + hh;
            if (sec == 3) {
                s16x4 pv;
                #pragma unroll
                for (int r = 0; r < 4; ++r) pv[r] = f2bf(acc[mt][nt][r]);
                *(s16x4*)(o3 + (((size_t)(bh * 64 + d)) << 10) + li0) = pv;
            } else {
                #pragma unroll
                for (int r = 0; r < 4; ++r) {
                    short bv = f2bf(acc[mt][nt][r]);
                    if (sec == 0)
                        o0[((size_t)(bh << 10) + li0 + r) * 64 + d] = bv;
                    else if (sec == 1)
                        o1[((size_t)bh * 1024 + li0 + r) * 128 + d] = bv;
                    else
                        o2[((size_t)bh * 1024 + li0 + r) * 128 + d] = bv;
                }
            }
        }
    }
}

// ---------------------------------------------------------------------------
// gemm_nt (EPI==1 only): final projection ctx @ WfcT -> out fp32.
// R8 structure: depth-1 counted-vmcnt dbuf, 1-D XCD swizzle; (row>>1)&3
// LDS swizzle.
// ---------------------------------------------------------------------------
template<int EPI, int NCOLS>
__global__ __launch_bounds__(256) void gemm_nt(
    const short* __restrict__ A, const short* __restrict__ BT,
    float* __restrict__ of)
{
    __shared__ short As[2][128 * 32];
    __shared__ short Bs[2][128 * 32];

    int nwg = gridDim.x * gridDim.y;
    int lin = blockIdx.y * gridDim.x + blockIdx.x;
    int cpx = nwg >> 3;
    int swb = (lin & 7) * cpx + (lin >> 3);
    int bx = swb % gridDim.x, by = swb / gridDim.x;
    int m0 = by * 128, n0 = bx * 128;

    int tid = threadIdx.x;
    int w = tid >> 6, lane = tid & 63;
    int wm = w >> 1, wn = w & 1;
    int lq = lane & 15, lg = lane >> 4;

    f32x4 zero = {0.f, 0.f, 0.f, 0.f};
    f32x4 acc[4][4];
    #pragma unroll
    for (int i = 0; i < 4; ++i)
        #pragma unroll
        for (int j = 0; j < 4; ++j) acc[i][j] = zero;

    int swz = (((lane & 3) ^ ((lane >> 3) & 3)) << 3);   // (srow>>1)&3 pre-swizzle
    int srow = lane >> 2;
    const short* aBase = A  + (size_t)(m0 + (w << 5) + srow) * 1024 + swz;
    const short* bBase = BT + (size_t)(n0 + (w << 5) + srow) * 1024 + swz;
    int dOff = w * 1024;

    GLDS16(aBase, &As[0][dOff]);
    GLDS16(aBase + 16 * 1024, &As[0][dOff + 512]);
    GLDS16(bBase, &Bs[0][dOff]);
    GLDS16(bBase + 16 * 1024, &Bs[0][dOff + 512]);

    int cur = 0;
    for (int kt = 0; kt < 1024; kt += 32) {
        if (kt + 32 < 1024) {
            int nxt = cur ^ 1;
            GLDS16(aBase + kt + 32, &As[nxt][dOff]);
            GLDS16(aBase + kt + 32 + 16 * 1024, &As[nxt][dOff + 512]);
            GLDS16(bBase + kt + 32, &Bs[nxt][dOff]);
            GLDS16(bBase + kt + 32 + 16 * 1024, &Bs[nxt][dOff + 512]);
            asm volatile("s_waitcnt vmcnt(4)" ::: "memory");
        } else {
            asm volatile("s_waitcnt vmcnt(0)" ::: "memory");
        }
        __builtin_amdgcn_s_barrier();
        asm volatile("" ::: "memory");

        s16x8 af[4], bfr[4];
        #pragma unroll
        for (int mt = 0; mt < 4; ++mt) {
            int row = wm * 64 + mt * 16 + lq;
            af[mt] = ldlds(As[cur], (row * 64 + lg * 16) ^ (((row >> 1) & 3) << 4));
        }
        #pragma unroll
        for (int nt = 0; nt < 4; ++nt) {
            int row = wn * 64 + nt * 16 + lq;
            bfr[nt] = ldlds(Bs[cur], (row * 64 + lg * 16) ^ (((row >> 1) & 3) << 4));
        }
        #pragma unroll
        for (int mt = 0; mt < 4; ++mt)
            #pragma unroll
            for (int nt = 0; nt < 4; ++nt)
                acc[mt][nt] = mfma16(af[mt], bfr[nt], acc[mt][nt]);

        asm volatile("" ::: "memory");
        __builtin_amdgcn_s_barrier();
        cur ^= 1;
    }

    #pragma unroll
    for (int nt = 0; nt < 4; ++nt) {
        int n = n0 + wn * 64 + nt * 16 + lq;
        #pragma unroll
        for (int mt = 0; mt < 4; ++mt) {
            int mb = m0 + wm * 64 + mt * 16 + lg * 4;
            #pragma unroll
            for (int r = 0; r < 4; ++r)
                of[(size_t)(mb + r) * NCOLS + n] = acc[mt][nt][r];
        }
    }
}

// ---------------------------------------------------------------------------
// attn: flash attention (best measured): grid 1024 = 64 bh x 16 q-tiles,
// bh = xg*8+(j&7) / qt = 15-(j>>3); K dbuf counted vmcnt; V single-buffered
// staged at loop bottom; defer-max, cvt_pk, setprio, b128 mask reads.
// NEW: V swizzle upgraded (vrow&3 -> (vrow>>1)&3) to kill the remaining
// 4-way bank conflict on the PV ds_read (same transformation as gemm R22).
// ---------------------------------------------------------------------------
__global__ __launch_bounds__(256) void attn_kernel(
    const short* __restrict__ qb, const short* __restrict__ k1cat,
    const short* __restrict__ k2cat, const short* __restrict__ vtb,
    const short* __restrict__ qpb, const int* __restrict__ PM,
    const int* __restrict__ qmask, short* __restrict__ ctx)
{
    __shared__ short K1s[2][32 * 128];
    __shared__ short K2s[2][32 * 128];
    __shared__ short Vs[64 * 32];         // single buffer (staged post-barrier)
    __shared__ int   PMs[2][64];

    int bid = blockIdx.x;                 // 1024 blocks
    int xg = bid & 7, j = bid >> 3;       // xg = XCD, j in [0,128)
    int bh = xg * 8 + (j & 7);            // 8 bh panels per XCD (L2 reuse)
    int qt = 15 - (j >> 3);               // descending qt: big blocks first
    int b = bh >> 4, h = bh & 15;

    int w = threadIdx.x >> 6, lane = threadIdx.x & 63;
    int lq = lane & 15, lg = lane >> 4;

    auto STAGE_K = [&](int d, int K0) {
        #pragma unroll
        for (int i = 0; i < 4; ++i) {
            int g = w * 4 + i;
            if (g < 8) {
                int row = g * 4 + (lane >> 4);
                int colb = ((lane & 15) << 4) ^ ((row & 7) << 4);
                const short* src = k1cat + ((size_t)bh * 1024 + K0 + row) * 128 + (colb >> 1);
                GLDS16(src, &K1s[d][g * 512]);
            } else {
                int gg = g - 8;
                int row = gg * 4 + (lane >> 4);
                int colb = ((lane & 15) << 4) ^ ((row & 7) << 4);
                const short* src = k2cat + ((size_t)bh * 1024 + K0 + row) * 128 + (colb >> 1);
                GLDS16(src, &K2s[d][gg * 512]);
            }
        }
        if (w == 0) {
            GLDS4(PM + b * 1088 + K0 + lane, &PMs[d][0]);
        }
    };
    auto STAGE_V = [&](int K0) {
        int row = w * 16 + (lane >> 2);
        int colb = ((lane & 3) << 4) ^ (((row >> 1) & 3) << 4);   // (row>>1)&3
        const short* src = vtb + ((size_t)bh * 64 + row) * 1024 + K0 + (colb >> 1);
        GLDS16(src, &Vs[w * 512]);
    };

    f32x4 zero = {0.f, 0.f, 0.f, 0.f};

    int q0 = qt * 64 + w * 16;
    int q_glob = q0 + lq;

    const short* qrow  = qb  + ((size_t)bh * SEQ + q_glob) * DHEAD;
    const short* qprow = qpb + ((size_t)h  * SEQ + q_glob) * DHEAD;
    s16x8 qf0  = *(const s16x8*)(qrow + lg * 8);
    s16x8 qf1  = *(const s16x8*)(qrow + 32 + lg * 8);
    s16x8 qpf0 = *(const s16x8*)(qprow + lg * 8);
    s16x8 qpf1 = *(const s16x8*)(qprow + 32 + lg * 8);
    int qm_q = qmask[b * SEQ + q_glob] & 1;
    asm volatile("s_waitcnt vmcnt(0)" ::: "memory");

    f32x4 accO[4];
    #pragma unroll
    for (int i = 0; i < 4; ++i) accO[i] = zero;
    float m_run = -1e30f, l_run = 0.f;

    int nslab = 2 * qt + 2;
    STAGE_K(0, 0);
    STAGE_V(0);

    #pragma unroll 1
    for (int t = 0; t < nslab; ++t) {
        int cur = t & 1;
        if (t + 1 < nslab) {
            STAGE_K(cur ^ 1, (t + 1) * 32);
            if (w == 0) asm volatile("s_waitcnt vmcnt(5)" ::: "memory");
            else        asm volatile("s_waitcnt vmcnt(4)" ::: "memory");
        } else {
            asm volatile("s_waitcnt vmcnt(0)" ::: "memory");
        }
        __builtin_amdgcn_s_barrier();
        asm volatile("" ::: "memory");

        int K0 = t * 32;
        if (K0 <= q0 + 15) {
            const short* b1 = K1s[cur];
            const short* b2 = K2s[cur];

            f32x4 s1v[2], s2v[2];
            __builtin_amdgcn_s_setprio(1);
            #pragma unroll
            for (int hh = 0; hh < 2; ++hh) {
                int row = hh * 16 + lq;
                int ro = row * 256 + (lg << 4);
                int sw = (row & 7) << 4;
                f32x4 tv = zero, uv = zero;
                tv = mfma16(ldlds(b1, (ro      ) ^ sw), qf0,  tv);
                tv = mfma16(ldlds(b1, (ro +  64) ^ sw), qf1,  tv);
                tv = mfma16(ldlds(b1, (ro + 128) ^ sw), qpf0, tv);
                tv = mfma16(ldlds(b1, (ro + 192) ^ sw), qpf1, tv);
                s1v[hh] = tv;
                uv = mfma16(ldlds(b2, (ro      ) ^ sw), qf0,  uv);
                uv = mfma16(ldlds(b2, (ro +  64) ^ sw), qf1,  uv);
                uv = mfma16(ldlds(b2, (ro + 128) ^ sw), qpf0, uv);
                uv = mfma16(ldlds(b2, (ro + 192) ^ sw), qpf1, uv);
                s2v[hh] = uv;
            }
            __builtin_amdgcn_s_setprio(0);

            int4 pmv0 = *(const int4*)&PMs[cur][lg * 4];
            int4 pmv1 = *(const int4*)&PMs[cur][16 + lg * 4];
            int pme[8] = {pmv0.x, pmv0.y, pmv0.z, pmv0.w,
                          pmv1.x, pmv1.y, pmv1.z, pmv1.w};

            float sv[8];
            #pragma unroll
            for (int i = 0; i < 8; ++i) {
                int hh = i >> 2, r = i & 3;
                int k_idx = K0 + hh * 16 + lg * 4 + r;
                int pm = pme[i];
                float s = ((pm & 1) == qm_q) ? s1v[hh][r] : s2v[hh][r];
                if (k_idx > q_glob || (pm & 2)) s = -INFINITY;
                sv[i] = s;
            }
            float tm = sv[0];
            #pragma unroll
            for (int i = 1; i < 8; ++i) tm = fmaxf(tm, sv[i]);
            tm = fmaxf(tm, __shfl_xor(tm, 16));
            tm = fmaxf(tm, __shfl_xor(tm, 32));

            if (!__all(tm <= m_run + 8.0f)) {
                float m_new = fmaxf(m_run, tm);
                float scale = __expf(m_run - m_new);
                m_run = m_new;
                l_run *= scale;
                f32x4 scv;
                scv[0] = __shfl(scale, lg * 4 + 0);
                scv[1] = __shfl(scale, lg * 4 + 1);
                scv[2] = __shfl(scale, lg * 4 + 2);
                scv[3] = __shfl(scale, lg * 4 + 3);
                #pragma unroll
                for (int dt = 0; dt < 4; ++dt) accO[dt] *= scv;
            }

            float p[8]; float ps = 0.f;
            #pragma unroll
            for (int i = 0; i < 8; ++i) { p[i] = __expf(sv[i] - m_run); ps += p[i]; }
            ps += __shfl_xor(ps, 16);
            ps += __shfl_xor(ps, 32);
            l_run += ps;

            unsigned dA0 = cvtpk(p[0], p[1]);
            unsigned dA1 = cvtpk(p[2], p[3]);
            unsigned dB0 = cvtpk(p[4], p[5]);
            unsigned dB1 = cvtpk(p[6], p[7]);
            int sl0 = lq + ((lg & 1) << 5);
            int sl1 = sl0 + 16;
            unsigned a0 = (unsigned)__shfl((int)dA0, sl0), a1 = (unsigned)__shfl((int)dA1, sl0);
            unsigned a2 = (unsigned)__shfl((int)dA0, sl1), a3 = (unsigned)__shfl((int)dA1, sl1);
            unsigned c0 = (unsigned)__shfl((int)dB0, sl0), c1 = (unsigned)__shfl((int)dB1, sl0);
            unsigned c2 = (unsigned)__shfl((int)dB0, sl1), c3 = (unsigned)__shfl((int)dB1, sl1);
            bool hi = (lg >= 2);
            union { unsigned u[4]; s16x8 v; } pa;
            pa.u[0] = hi ? c0 : a0; pa.u[1] = hi ? c1 : a1;
            pa.u[2] = hi ? c2 : a2; pa.u[3] = hi ? c3 : a3;

            __builtin_amdgcn_s_setprio(1);
            #pragma unroll
            for (int dt = 0; dt < 4; ++dt) {
                int vrow = dt * 16 + lq;
                int voff = (vrow * 64 + (lg << 4)) ^ (((vrow >> 1) & 3) << 4);
                accO[dt] = mfma16(pa.v, ldlds(Vs, voff), accO[dt]);
            }
            __builtin_amdgcn_s_setprio(0);
        }

        asm volatile("" ::: "memory");
        __builtin_amdgcn_s_barrier();     // all waves done with Vs + buf[cur]
        if (t + 1 < nslab) STAGE_V((t + 1) * 32);
    }

    float inv = 1.0f / l_run;
    f32x4 invv;
    invv[0] = __shfl(inv, lg * 4 + 0);
    invv[1] = __shfl(inv, lg * 4 + 1);
    invv[2] = __shfl(inv, lg * 4 + 2);
    invv[3] = __shfl(inv, lg * 4 + 3);
    #pragma unroll
    for (int dt = 0; dt < 4; ++dt) {
        #pragma unroll
        for (int r = 0; r < 4; ++r) {
            int qo = q0 + lg * 4 + r;
            size_t off = ((size_t)(b * SEQ + qo)) * DMODEL + h * DHEAD + dt * 16 + lq;
            ctx[off] = f2bf(accO[dt][r] * invv[r]);
        }
    }
}

// ---------------------------------------------------------------------------
extern "C" void kernel_launch(void* const* d_in, const int* in_sizes, int n_in,
                              void* d_out, int out_size, void* d_ws, size_t ws_size,
                              hipStream_t stream) {
    const float* embed = (const float*)d_in[0];
    const int*   umask = (const int*)d_in[1];
    const int*   qmask = (const int*)d_in[2];
    const float* Wqkv  = (const float*)d_in[3];
    const float* Wpos  = (const float*)d_in[4];
    const float* Wfc   = (const float*)d_in[5];
    float* out = (float*)d_out;

    char* w = (char*)d_ws;
    short* qb    = (short*)(w + (0ull  << 20));  // [B][H][L][64]    8 MB
    short* vtb   = (short*)(w + (8ull  << 20));  // [B][H][64][L]    8 MB
    short* qpb   = (short*)(w + (16ull << 20));  // [H][L][64]       2 MB
    short* ctx   = (short*)(w + (18ull << 20));  // [B*L][1024]      8 MB
    short* ebf   = ctx;                          // aliased: ebf dead before attn
    short* k1cat = (short*)(w + (26ull << 20));  // [B][H][L][128]  16 MB
    short* k2cat = (short*)(w + (42ull << 20));  // [B][H][L][128]  16 MB
    int*   PM    = (int*)  (w + (58ull << 20));  // [4][1088]       ~17 KB
    short* WqkvT = (short*)(w + (59ull << 20));  // [4096][1024]     8 MB
    short* WfcT  = (short*)(w + (67ull << 20));  // [1024][1024]     2 MB

    hipLaunchKernelGGL(prep_a_kernel, dim3(3072), dim3(256), 0, stream,
                       embed, Wqkv, ebf, WqkvT);
    hipLaunchKernelGGL(gemm_qkv_fused, dim3(900), dim3(512), 0, stream,
                       ebf, WqkvT, qb, k1cat, k2cat, vtb,
                       qmask, umask, Wpos, Wfc, PM, qpb, WfcT);
    hipLaunchKernelGGL(attn_kernel, dim3(1024), dim3(256), 0, stream,
                       qb, k1cat, k2cat, vtb, qpb, PM, qmask, ctx);
    hipLaunchKernelGGL((gemm_nt<1, 1024>), dim3(8, 32), dim3(256), 0, stream,
                       ctx, WfcT, out);
}